// Round 6
// baseline (224.212 us; speedup 1.0000x reference)
//
#include <hip/hip_runtime.h>

#define NGRAPH 256
#define NN     128   // nodes per graph
#define NT     16    // templates
#define NM     10    // template nodes
#define OUTER_IT 5
#define SINK_IT  20

// K = exp(-20*tens) = exp2(-20*log2(e)*tens)
#define SC1  28.85390081777927f    // 20*log2(e)
#define SC2  57.70780163555854f    // 40*log2(e)

// P row stride (floats): 48B, 16B-aligned -> b128 gather ops.
#define PSTR 12

typedef unsigned long long u64;
typedef float v2f __attribute__((ext_vector_type(2)));
typedef float v4f __attribute__((ext_vector_type(4)));

static __device__ __forceinline__ v2f pkfma(v2f a, v2f b, v2f c) {
  return __builtin_elementwise_fma(a, b, c);
}
static __device__ __forceinline__ v2f bc2(float s) { return (v2f){s, s}; }

// DPP xor-butterfly add within a 16-lane row (masks {1,2,7,15} span (Z2)^4).
template <int CTRL>
__device__ __forceinline__ float dpp_add(float a) {
  int t = __builtin_amdgcn_update_dpp(0, __float_as_int(a), CTRL, 0xf, 0xf, true);
  return a + __int_as_float(t);
}
// Sum over each 32-lane group; result broadcast to all lanes of the group.
// (Baseline-proven form: ds_swizzle xor-16. Rounds 3-4 carried a permlane
// variant that was never isolated; reverted to remove the confound.)
__device__ __forceinline__ float allsum32(float x) {
  x = dpp_add<0xB1>(x);    // quad_perm xor 1
  x = dpp_add<0x4E>(x);    // quad_perm xor 2
  x = dpp_add<0x141>(x);   // row_half_mirror: xor 7
  x = dpp_add<0x140>(x);   // row_mirror: xor 15
  int sw = __builtin_amdgcn_ds_swizzle(__float_as_int(x), 0x401F); // xor 16
  return x + __int_as_float(sw);
}

// Pop lowest set bit of a 128-bit mask (lo,hi); returns NN (=zero row) when
// empty. Fully if-convertible: no branches, m&(m-1) is 0-safe, ctz operand
// forced nonzero. Empty pops load the all-zero LDS row -> S += +0.0, which is
// bitwise identity (all partial sums are >= +0).
static __device__ __forceinline__ int pop1(u64& lo, u64& hi) {
  u64 t   = (lo != 0) ? lo : hi;
  u64 ts  = t | (u64)(t == 0);            // safe ctz operand
  int base = (lo != 0) ? 0 : 64;
  int k = ((lo | hi) != 0) ? base + (int)__builtin_ctzll(ts) : NN;
  u64 nlo = lo & (lo - 1);                // 0 stays 0
  u64 nhi = (lo != 0) ? hi : (hi & (hi - 1));
  lo = nlo; hi = nhi;
  return k;
}

// 32 lanes per (graph b, template t) pair, 2 pairs per 64-thread single-wave
// block (empirically optimal decomposition; 64-lane and 16-lane variants both
// measured worse). Lane owns 4 rows r = sub + 32*c.
__global__ __launch_bounds__(64, 2)
void tgw_kernel(const int* __restrict__ ei,
                const float* __restrict__ tadj,
                const float* __restrict__ q0g,
                float* __restrict__ out,
                int E, int ne) {
  const int lane = threadIdx.x;
  const int p    = lane >> 5;        // pair slot 0/1
  const int sub  = lane & 31;
  const int b    = blockIdx.x >> 3;
  const int t0   = (blockIdx.x & 7) * 2;   // templates t0, t0+1

  __shared__ __align__(16) unsigned adj[NN][4];        // 2 KB
  __shared__ __align__(16) float Pls[2][NN + 1][PSTR]; // 12.1 KB; row NN = zeros
  __shared__ __align__(16) v2f C2T[2][NM][6];          // SC2*C2, [m][jpair]
  __shared__ float q0s[2][NM];

  // ---- stage ----
  for (int i = lane; i < NN * 4; i += 64) (&adj[0][0])[i] = 0u;
  // zero row NN of both P buffers (never overwritten: writeback touches 0..127)
  if (lane < 2 * PSTR) Pls[lane / PSTR][NN][lane % PSTR] = 0.f;
  // C2T[tt][m][jp] = SC2 * { C2[2jp][m], C2[2jp+1][m] }  (transposed pairs)
  for (int i = lane; i < 2 * NM * 5; i += 64) {
    int tt = i / 50, r = i % 50, m = r / 5, jp = r % 5;
    const float* bp = tadj + (t0 + tt) * NM * NM + m;
    C2T[tt][m][jp] = (v2f){bp[(2 * jp) * NM], bp[(2 * jp + 1) * NM]} * SC2;
  }
  if (lane < 2 * NM) q0s[lane / NM][lane % NM] = q0g[t0 * NM + lane];
  __syncthreads();

  // symmetric 0/1 adjacency from the edge list (dups/self-loops harmless)
  const int* srcp = ei;
  const int* dstp = ei + E;
  const int ebase = b * ne;
  for (int e = lane; e < ne; e += 64) {
    int s = srcp[ebase + e] & (NN - 1);
    int d = dstp[ebase + e] & (NN - 1);
    atomicOr(&adj[s][d >> 5], 1u << (d & 31));
    atomicOr(&adj[d][s >> 5], 1u << (s & 31));
  }
  __syncthreads();

  // ---- per-pair constants ----
  float qv[NM];
  {
    float mx = q0s[p][0];
    #pragma unroll
    for (int j = 1; j < NM; ++j) mx = fmaxf(mx, q0s[p][j]);
    float s = 0.f;
    #pragma unroll
    for (int j = 0; j < NM; ++j) { qv[j] = __expf(q0s[p][j] - mx); s += qv[j]; }
    float inv = __builtin_amdgcn_rcpf(s);
    #pragma unroll
    for (int j = 0; j < NM; ++j) qv[j] *= inv;
  }
  v2f q2[5];
  #pragma unroll
  for (int jp = 0; jp < 5; ++jp) q2[jp] = (v2f){qv[2 * jp], qv[2 * jp + 1]};

  // fq2[jp] = -SC1 * f2q[jpair]; f2q[j] = sum_m C2[j][m]^2 q[m]
  // C2 = C2T/SC2 => factor -SC1/SC2^2 = -1/(4*SC1)
  // qC2T[jp] = sum_m q[m] * C2T[m][jp]   (for the o==0 analytic cost)
  v2f fq2[5], qC2T[5];
  {
    #pragma unroll
    for (int jp = 0; jp < 5; ++jp) { fq2[jp] = (v2f){0.f, 0.f}; qC2T[jp] = (v2f){0.f, 0.f}; }
    #pragma unroll
    for (int m = 0; m < NM; ++m) {
      v2f qb = bc2(qv[m]);
      #pragma unroll
      for (int jp = 0; jp < 5; ++jp) {
        v2f c = C2T[p][m][jp];
        fq2[jp]  = pkfma(c * c, qb, fq2[jp]);
        qC2T[jp] = pkfma(c, qb, qC2T[jp]);
      }
    }
    const float f = -1.0f / (4.0f * SC1);
    #pragma unroll
    for (int jp = 0; jp < 5; ++jp) fq2[jp] *= f;
  }

  const float pw = 1.0f / 128.0f;
  float f1p[4], m1f1[4];
  #pragma unroll
  for (int c = 0; c < 4; ++c) {
    uint4 mm = *(const uint4*)&adj[sub + 32 * c][0];
    u64 m0 = mm.x | ((u64)mm.y << 32), m1 = mm.z | ((u64)mm.w << 32);
    f1p[c]  = (float)(__popcll(m0) + __popcll(m1)) * pw;   // C1*C1 == C1
    m1f1[c] = -SC1 * f1p[c];
  }

  const float* Pbase = &Pls[p][0][0];

  // S = (C1 @ P) for TWO rows per loop trip, single BRANCH-FREE body: both
  // rows' pops are if-converted (pop1) and both rows' 6 loads issue before
  // either accumulation (compiler waits lgkmcnt(3), not 0). Wave trip count =
  // max(maxdeg(A), maxdeg(B)) instead of the serial walk's sum -> ~1.8x fewer
  // ~120cy load-latency stall slots. Exhausted lanes pop k=NN (zero row):
  // S += +0.0 is bitwise identity. Per-row pop order ascending-k -> bit-exact.
  auto gatherPair = [&](int ra, int rb, v2f* SA, v2f* SB) {
    uint4 ma = *(const uint4*)&adj[ra][0];
    uint4 mb = *(const uint4*)&adj[rb][0];
    u64 aLo = ma.x | ((u64)ma.y << 32), aHi = ma.z | ((u64)ma.w << 32);
    u64 bLo = mb.x | ((u64)mb.y << 32), bHi = mb.z | ((u64)mb.w << 32);
    #pragma unroll
    for (int h = 0; h < 5; ++h) { SA[h] = (v2f){0.f, 0.f}; SB[h] = (v2f){0.f, 0.f}; }
    while ((aLo | aHi | bLo | bHi) != 0u) {
      int ka = pop1(aLo, aHi);
      int kb = pop1(bLo, bHi);
      const float* rowA = Pbase + ka * PSTR;
      const float* rowB = Pbase + kb * PSTR;
      v4f A0 = *(const v4f*)rowA;
      v4f A1 = *(const v4f*)(rowA + 4);
      v2f A2 = *(const v2f*)(rowA + 8);
      v4f B0 = *(const v4f*)rowB;
      v4f B1 = *(const v4f*)(rowB + 4);
      v2f B2 = *(const v2f*)(rowB + 8);
      SA[0] += A0.xy; SA[1] += A0.zw; SA[2] += A1.xy; SA[3] += A1.zw; SA[4] += A2;
      SB[0] += B0.xy; SB[1] += B0.zw; SB[2] += B1.xy; SB[3] += B1.zw; SB[4] += B2;
    }
  };

  // Gather all 4 lane rows (two paired walks), unpack to scalar S.
  auto gather4 = [&](float Sm[4][NM]) {
    v2f S2[4][5];
    gatherPair(sub + 32 * 0, sub + 32 * 1, S2[0], S2[1]);
    gatherPair(sub + 32 * 2, sub + 32 * 3, S2[2], S2[3]);
    #pragma unroll
    for (int c = 0; c < 4; ++c)
      #pragma unroll
      for (int h = 0; h < 5; ++h) { Sm[c][2 * h] = S2[c][h].x; Sm[c][2 * h + 1] = S2[c][h].y; }
  };

  // arg2[c][jp] = -SC1*tens (packed over jpairs), from scalar S[m] per row
  auto costFromS = [&](float Sm[4][NM], v2f arg2[4][5]) {
    #pragma unroll
    for (int c = 0; c < 4; ++c) {
      #pragma unroll
      for (int jp = 0; jp < 5; ++jp) arg2[c][jp] = fq2[jp] + bc2(m1f1[c]);
    }
    #pragma unroll
    for (int m = 0; m < NM; ++m) {
      v4f X = *(const v4f*)&C2T[p][m][0];   // jp 0,1
      v4f Y = *(const v4f*)&C2T[p][m][2];   // jp 2,3
      v2f Z = *(const v2f*)&C2T[p][m][4];   // jp 4
      #pragma unroll
      for (int c = 0; c < 4; ++c) {
        v2f sb = bc2(Sm[c][m]);
        arg2[c][0] = pkfma(sb, X.xy, arg2[c][0]);
        arg2[c][1] = pkfma(sb, X.zw, arg2[c][1]);
        arg2[c][2] = pkfma(sb, Y.xy, arg2[c][2]);
        arg2[c][3] = pkfma(sb, Y.zw, arg2[c][3]);
        arg2[c][4] = pkfma(sb, Z,    arg2[c][4]);
      }
    }
  };

  v2f K2[4][5], v2[5], arg2[4][5];
  float uu[4];

  for (int o = 0; o < OUTER_IT; ++o) {
    // ---- cost -> arg2 -> K = exp2(arg) ----
    if (o == 0) {
      // P0 = p q^T => S[c][m] = f1p[c]*q[m] => sum_m S C2T = f1p[c]*qC2T
      #pragma unroll
      for (int c = 0; c < 4; ++c) {
        v2f fb = bc2(f1p[c]);
        v2f ob = bc2(m1f1[c]);
        #pragma unroll
        for (int jp = 0; jp < 5; ++jp)
          arg2[c][jp] = pkfma(fb, qC2T[jp], fq2[jp] + ob);
      }
    } else {
      float Sm[4][NM];
      gather4(Sm);
      costFromS(Sm, arg2);
    }
    #pragma unroll
    for (int c = 0; c < 4; ++c)
      #pragma unroll
      for (int jp = 0; jp < 5; ++jp)
        K2[c][jp] = (v2f){exp2f(arg2[c][jp].x), exp2f(arg2[c][jp].y)};

    // ---- Sinkhorn (v starts at ones) ----
    #pragma unroll
    for (int jp = 0; jp < 5; ++jp) v2[jp] = (v2f){1.f, 1.f};
    for (int it = 0; it < SINK_IT; ++it) {
      #pragma unroll
      for (int c = 0; c < 4; ++c) {
        v2f d2 = K2[c][0] * v2[0];
        d2 = pkfma(K2[c][1], v2[1], d2);
        d2 = pkfma(K2[c][2], v2[2], d2);
        d2 = pkfma(K2[c][3], v2[3], d2);
        d2 = pkfma(K2[c][4], v2[4], d2);
        uu[c] = pw * __builtin_amdgcn_rcpf(d2.x + d2.y);
      }
      #pragma unroll
      for (int jp = 0; jp < 5; ++jp) {
        v2f w2 = K2[0][jp] * bc2(uu[0]);
        w2 = pkfma(K2[1][jp], bc2(uu[1]), w2);
        w2 = pkfma(K2[2][jp], bc2(uu[2]), w2);
        w2 = pkfma(K2[3][jp], bc2(uu[3]), w2);
        float cx = allsum32(w2.x);
        float cy = allsum32(w2.y);
        v2[jp] = (v2f){q2[jp].x * __builtin_amdgcn_rcpf(cx),
                       q2[jp].y * __builtin_amdgcn_rcpf(cy)};
      }
    }

    // ---- P = diag(u) K diag(v) -> LDS ----
    __syncthreads();   // single-wave block: just drains LDS ops, ~free
    #pragma unroll
    for (int c = 0; c < 4; ++c) {
      v2f ub = bc2(uu[c]);
      v2f x0 = K2[c][0] * ub * v2[0];
      v2f x1 = K2[c][1] * ub * v2[1];
      v2f x2 = K2[c][2] * ub * v2[2];
      v2f x3 = K2[c][3] * ub * v2[3];
      v2f x4 = K2[c][4] * ub * v2[4];
      float* row = &Pls[p][sub + 32 * c][0];
      *(v4f*)row       = (v4f){x0.x, x0.y, x1.x, x1.y};
      *(v4f*)(row + 4) = (v4f){x2.x, x2.y, x3.x, x3.y};
      *(v2f*)(row + 8) = x4;
    }
    __syncthreads();
  }

  // ---- GW = sum_ij tens(P)_ij * P_ij,  tens = arg * (-1/SC1) ----
  float acc = 0.f;
  {
    float Sm[4][NM];
    gather4(Sm);
    costFromS(Sm, arg2);
    const v2f nf = bc2(-1.0f / SC1);
    v2f acc2 = (v2f){0.f, 0.f};
    #pragma unroll
    for (int c = 0; c < 4; ++c) {
      v2f ub = bc2(uu[c]);
      #pragma unroll
      for (int jp = 0; jp < 5; ++jp) {
        v2f Pv = K2[c][jp] * ub * v2[jp];
        acc2 = pkfma(arg2[c][jp] * nf, Pv, acc2);
      }
    }
    acc = acc2.x + acc2.y;
  }
  float total = allsum32(acc);
  if (sub == 0) out[b * NT + t0 + p] = total;
}

extern "C" void kernel_launch(void* const* d_in, const int* in_sizes, int n_in,
                              void* d_out, int out_size, void* d_ws, size_t ws_size,
                              hipStream_t stream) {
  // inputs: 0 x(f32, unused) 1 edge_index(int32) 2 batch(int32, unused)
  //         3 tplt_adjacencies(f32) 4 tplt_features(f32, unused) 5 q0(f32)
  const int* ei   = (const int*)d_in[1];
  const float* c2 = (const float*)d_in[3];
  const float* q0 = (const float*)d_in[5];
  float* out      = (float*)d_out;
  const int E  = in_sizes[1] / 2;
  const int ne = E / NGRAPH;
  tgw_kernel<<<dim3(NGRAPH * 8), dim3(64), 0, stream>>>(ei, c2, q0, out, E, ne);
}

// Round 7
// 200.617 us; speedup vs baseline: 1.1176x; 1.1176x over previous
//
#include <hip/hip_runtime.h>

#define NGRAPH 256
#define NN     128   // nodes per graph
#define NT     16    // templates
#define NM     10    // template nodes
#define OUTER_IT 5
#define SINK_IT  20

// K = exp(-20*tens) = exp2(-20*log2(e)*tens)
#define SC1  28.85390081777927f    // 20*log2(e)
#define SC2  57.70780163555854f    // 40*log2(e)

typedef unsigned long long u64;
typedef float v2f __attribute__((ext_vector_type(2)));
typedef float v4f __attribute__((ext_vector_type(4)));

static __device__ __forceinline__ v2f pkfma(v2f a, v2f b, v2f c) {
  return __builtin_elementwise_fma(a, b, c);
}
static __device__ __forceinline__ v2f bc2(float s) { return (v2f){s, s}; }

// DPP xor-butterfly add within a 16-lane row (masks {1,2,7,15} span (Z2)^4).
template <int CTRL>
__device__ __forceinline__ float dpp_add(float a) {
  int t = __builtin_amdgcn_update_dpp(0, __float_as_int(a), CTRL, 0xf, 0xf, true);
  return a + __int_as_float(t);
}
// Sum over each 32-lane group; result broadcast to all lanes of the group.
__device__ __forceinline__ float allsum32(float x) {
  x = dpp_add<0xB1>(x);    // quad_perm xor 1
  x = dpp_add<0x4E>(x);    // quad_perm xor 2
  x = dpp_add<0x141>(x);   // row_half_mirror: xor 7
  x = dpp_add<0x140>(x);   // row_mirror: xor 15
  int sw = __builtin_amdgcn_ds_swizzle(__float_as_int(x), 0x401F); // xor 16
  return x + __int_as_float(sw);
}

// 32 lanes per (graph b, template t) pair, 2 pairs per 64-thread single-wave
// block. Lane owns 4 rows r = sub + 32*c. Adjacency: LDS bitmask (shared).
// P: LDS fp32, row stride 12 floats. All fp32 math packed 2-wide over the
// 10-column axis (v_pk_fma_f32).
//
// SESSION NOTE (6 experiments, all regressed — this exact form is the local
// optimum): b64/stride-14 LDS (+21%), 64-lane pairs (+35%), 16-lane pairs
// (+4%), joint 2-row gather (+6%), 2-deep pipelined gather (+8%), branch-free
// paired gather w/ zero-row (+17%). Duration tracks wave-executed VALU work;
// occupancy gains do not convert; bank conflicts (8.3M) are pattern-inherent
// to the random-neighbor gather; HBM at 0.7% of peak. Do not "optimize" the
// gather by adding instructions.
__global__ __launch_bounds__(64, 2)
void tgw_kernel(const int* __restrict__ ei,
                const float* __restrict__ tadj,
                const float* __restrict__ q0g,
                float* __restrict__ out,
                int E, int ne) {
  const int lane = threadIdx.x;
  const int p    = lane >> 5;        // pair slot 0/1
  const int sub  = lane & 31;
  const int b    = blockIdx.x >> 3;
  const int t0   = (blockIdx.x & 7) * 2;   // templates t0, t0+1

  __shared__ __align__(16) unsigned adj[NN][4];    // 2 KB
  __shared__ __align__(16) float Pls[2][NN][12];   // 12 KB
  __shared__ __align__(16) v2f C2T[2][NM][6];      // SC2*C2, [m][jpair], row 48B
  __shared__ float q0s[2][NM];

  // ---- stage ----
  for (int i = lane; i < NN * 4; i += 64) (&adj[0][0])[i] = 0u;
  // C2T[tt][m][jp] = SC2 * { C2[2jp][m], C2[2jp+1][m] }  (transposed pairs)
  for (int i = lane; i < 2 * NM * 5; i += 64) {
    int tt = i / 50, r = i % 50, m = r / 5, jp = r % 5;
    const float* bp = tadj + (t0 + tt) * NM * NM + m;
    C2T[tt][m][jp] = (v2f){bp[(2 * jp) * NM], bp[(2 * jp + 1) * NM]} * SC2;
  }
  if (lane < 2 * NM) q0s[lane / NM][lane % NM] = q0g[t0 * NM + lane];
  __syncthreads();

  // symmetric 0/1 adjacency from the edge list (dups/self-loops harmless)
  const int* srcp = ei;
  const int* dstp = ei + E;
  const int ebase = b * ne;
  for (int e = lane; e < ne; e += 64) {
    int s = srcp[ebase + e] & (NN - 1);
    int d = dstp[ebase + e] & (NN - 1);
    atomicOr(&adj[s][d >> 5], 1u << (d & 31));
    atomicOr(&adj[d][s >> 5], 1u << (s & 31));
  }
  __syncthreads();

  // ---- per-pair constants ----
  float qv[NM];
  {
    float mx = q0s[p][0];
    #pragma unroll
    for (int j = 1; j < NM; ++j) mx = fmaxf(mx, q0s[p][j]);
    float s = 0.f;
    #pragma unroll
    for (int j = 0; j < NM; ++j) { qv[j] = __expf(q0s[p][j] - mx); s += qv[j]; }
    float inv = __builtin_amdgcn_rcpf(s);
    #pragma unroll
    for (int j = 0; j < NM; ++j) qv[j] *= inv;
  }
  v2f q2[5];
  #pragma unroll
  for (int jp = 0; jp < 5; ++jp) q2[jp] = (v2f){qv[2 * jp], qv[2 * jp + 1]};

  // fq2[jp] = -SC1 * f2q[jpair]; f2q[j] = sum_m C2[j][m]^2 q[m]
  // C2 = C2T/SC2 => factor -SC1/SC2^2 = -1/(4*SC1)
  // qC2T[jp] = sum_m q[m] * C2T[m][jp]   (for the o==0 analytic cost)
  v2f fq2[5], qC2T[5];
  {
    #pragma unroll
    for (int jp = 0; jp < 5; ++jp) { fq2[jp] = (v2f){0.f, 0.f}; qC2T[jp] = (v2f){0.f, 0.f}; }
    #pragma unroll
    for (int m = 0; m < NM; ++m) {
      v2f qb = bc2(qv[m]);
      #pragma unroll
      for (int jp = 0; jp < 5; ++jp) {
        v2f c = C2T[p][m][jp];
        fq2[jp]  = pkfma(c * c, qb, fq2[jp]);
        qC2T[jp] = pkfma(c, qb, qC2T[jp]);
      }
    }
    const float f = -1.0f / (4.0f * SC1);
    #pragma unroll
    for (int jp = 0; jp < 5; ++jp) fq2[jp] *= f;
  }

  const float pw = 1.0f / 128.0f;
  float f1p[4], m1f1[4];
  #pragma unroll
  for (int c = 0; c < 4; ++c) {
    uint4 mm = *(const uint4*)&adj[sub + 32 * c][0];
    u64 m0 = mm.x | ((u64)mm.y << 32), m1 = mm.z | ((u64)mm.w << 32);
    f1p[c]  = (float)(__popcll(m0) + __popcll(m1)) * pw;   // C1*C1 == C1
    m1f1[c] = -SC1 * f1p[c];
  }

  const float* Pbase = &Pls[p][0][0];
  // sparse gather S = (C1 @ P)[row r], packed pairs over m
  auto gatherRow = [&](int r, v2f* S2) {
    uint4 mm = *(const uint4*)&adj[r][0];
    u64 m0 = mm.x | ((u64)mm.y << 32), m1 = mm.z | ((u64)mm.w << 32);
    #pragma unroll
    for (int h = 0; h < 5; ++h) S2[h] = (v2f){0.f, 0.f};
    while (m0) {
      int k = (int)__builtin_ctzll(m0); m0 &= m0 - 1;
      const float* row = Pbase + k * 12;
      v4f A = *(const v4f*)row;
      v4f B = *(const v4f*)(row + 4);
      v2f C = *(const v2f*)(row + 8);
      S2[0] += A.xy; S2[1] += A.zw; S2[2] += B.xy; S2[3] += B.zw; S2[4] += C;
    }
    while (m1) {
      int k = 64 + (int)__builtin_ctzll(m1); m1 &= m1 - 1;
      const float* row = Pbase + k * 12;
      v4f A = *(const v4f*)row;
      v4f B = *(const v4f*)(row + 4);
      v2f C = *(const v2f*)(row + 8);
      S2[0] += A.xy; S2[1] += A.zw; S2[2] += B.xy; S2[3] += B.zw; S2[4] += C;
    }
  };

  // arg2[c][jp] = -SC1*tens (packed over jpairs), from scalar S[m] per row
  auto costFromS = [&](float Sm[4][NM], v2f arg2[4][5]) {
    #pragma unroll
    for (int c = 0; c < 4; ++c) {
      v2f ib = fq2[0] + bc2(m1f1[c]);
      arg2[c][0] = ib;
      #pragma unroll
      for (int jp = 1; jp < 5; ++jp) arg2[c][jp] = fq2[jp] + bc2(m1f1[c]);
    }
    #pragma unroll
    for (int m = 0; m < NM; ++m) {
      v4f X = *(const v4f*)&C2T[p][m][0];   // jp 0,1
      v4f Y = *(const v4f*)&C2T[p][m][2];   // jp 2,3
      v2f Z = *(const v2f*)&C2T[p][m][4];   // jp 4
      #pragma unroll
      for (int c = 0; c < 4; ++c) {
        v2f sb = bc2(Sm[c][m]);
        arg2[c][0] = pkfma(sb, X.xy, arg2[c][0]);
        arg2[c][1] = pkfma(sb, X.zw, arg2[c][1]);
        arg2[c][2] = pkfma(sb, Y.xy, arg2[c][2]);
        arg2[c][3] = pkfma(sb, Y.zw, arg2[c][3]);
        arg2[c][4] = pkfma(sb, Z,    arg2[c][4]);
      }
    }
  };

  v2f K2[4][5], v2[5], arg2[4][5];
  float uu[4];

  for (int o = 0; o < OUTER_IT; ++o) {
    // ---- cost -> arg2 -> K = exp2(arg) ----
    if (o == 0) {
      // P0 = p q^T => S[c][m] = f1p[c]*q[m] => sum_m S C2T = f1p[c]*qC2T
      #pragma unroll
      for (int c = 0; c < 4; ++c) {
        v2f fb = bc2(f1p[c]);
        v2f ob = bc2(m1f1[c]);
        #pragma unroll
        for (int jp = 0; jp < 5; ++jp)
          arg2[c][jp] = pkfma(fb, qC2T[jp], fq2[jp] + ob);
      }
    } else {
      float Sm[4][NM];
      #pragma unroll
      for (int c = 0; c < 4; ++c) {
        v2f S2[5];
        gatherRow(sub + 32 * c, S2);
        #pragma unroll
        for (int h = 0; h < 5; ++h) { Sm[c][2 * h] = S2[h].x; Sm[c][2 * h + 1] = S2[h].y; }
      }
      costFromS(Sm, arg2);
    }
    #pragma unroll
    for (int c = 0; c < 4; ++c)
      #pragma unroll
      for (int jp = 0; jp < 5; ++jp)
        K2[c][jp] = (v2f){exp2f(arg2[c][jp].x), exp2f(arg2[c][jp].y)};

    // ---- Sinkhorn (v starts at ones) ----
    #pragma unroll
    for (int jp = 0; jp < 5; ++jp) v2[jp] = (v2f){1.f, 1.f};
    for (int it = 0; it < SINK_IT; ++it) {
      #pragma unroll
      for (int c = 0; c < 4; ++c) {
        v2f d2 = K2[c][0] * v2[0];
        d2 = pkfma(K2[c][1], v2[1], d2);
        d2 = pkfma(K2[c][2], v2[2], d2);
        d2 = pkfma(K2[c][3], v2[3], d2);
        d2 = pkfma(K2[c][4], v2[4], d2);
        uu[c] = pw * __builtin_amdgcn_rcpf(d2.x + d2.y);
      }
      #pragma unroll
      for (int jp = 0; jp < 5; ++jp) {
        v2f w2 = K2[0][jp] * bc2(uu[0]);
        w2 = pkfma(K2[1][jp], bc2(uu[1]), w2);
        w2 = pkfma(K2[2][jp], bc2(uu[2]), w2);
        w2 = pkfma(K2[3][jp], bc2(uu[3]), w2);
        float cx = allsum32(w2.x);
        float cy = allsum32(w2.y);
        v2[jp] = (v2f){q2[jp].x * __builtin_amdgcn_rcpf(cx),
                       q2[jp].y * __builtin_amdgcn_rcpf(cy)};
      }
    }

    // ---- P = diag(u) K diag(v) -> LDS ----
    __syncthreads();   // single-wave block: just drains LDS ops, ~free
    #pragma unroll
    for (int c = 0; c < 4; ++c) {
      v2f ub = bc2(uu[c]);
      v2f x0 = K2[c][0] * ub * v2[0];
      v2f x1 = K2[c][1] * ub * v2[1];
      v2f x2 = K2[c][2] * ub * v2[2];
      v2f x3 = K2[c][3] * ub * v2[3];
      v2f x4 = K2[c][4] * ub * v2[4];
      float* row = &Pls[p][sub + 32 * c][0];
      *(v4f*)row       = (v4f){x0.x, x0.y, x1.x, x1.y};
      *(v4f*)(row + 4) = (v4f){x2.x, x2.y, x3.x, x3.y};
      *(v2f*)(row + 8) = x4;
    }
    __syncthreads();
  }

  // ---- GW = sum_ij tens(P)_ij * P_ij,  tens = arg * (-1/SC1) ----
  float acc = 0.f;
  {
    float Sm[4][NM];
    #pragma unroll
    for (int c = 0; c < 4; ++c) {
      v2f S2[5];
      gatherRow(sub + 32 * c, S2);
      #pragma unroll
      for (int h = 0; h < 5; ++h) { Sm[c][2 * h] = S2[h].x; Sm[c][2 * h + 1] = S2[h].y; }
    }
    costFromS(Sm, arg2);
    const v2f nf = bc2(-1.0f / SC1);
    v2f acc2 = (v2f){0.f, 0.f};
    #pragma unroll
    for (int c = 0; c < 4; ++c) {
      v2f ub = bc2(uu[c]);
      #pragma unroll
      for (int jp = 0; jp < 5; ++jp) {
        v2f Pv = K2[c][jp] * ub * v2[jp];
        acc2 = pkfma(arg2[c][jp] * nf, Pv, acc2);
      }
    }
    acc = acc2.x + acc2.y;
  }
  float total = allsum32(acc);
  if (sub == 0) out[b * NT + t0 + p] = total;
}

extern "C" void kernel_launch(void* const* d_in, const int* in_sizes, int n_in,
                              void* d_out, int out_size, void* d_ws, size_t ws_size,
                              hipStream_t stream) {
  // inputs: 0 x(f32, unused) 1 edge_index(int32) 2 batch(int32, unused)
  //         3 tplt_adjacencies(f32) 4 tplt_features(f32, unused) 5 q0(f32)
  const int* ei   = (const int*)d_in[1];
  const float* c2 = (const float*)d_in[3];
  const float* q0 = (const float*)d_in[5];
  float* out      = (float*)d_out;
  const int E  = in_sizes[1] / 2;
  const int ne = E / NGRAPH;
  tgw_kernel<<<dim3(NGRAPH * 8), dim3(64), 0, stream>>>(ei, c2, q0, out, E, ne);
}